// Round 8
// baseline (337.616 us; speedup 1.0000x reference)
//
#include <hip/hip_runtime.h>

#define NB   16
#define NSQ  1024
#define NSKV 1024
#define ND   256

typedef __bf16    bf16x8 __attribute__((ext_vector_type(8)));
typedef float     f32x4  __attribute__((ext_vector_type(4)));
typedef _Float16  f16x4  __attribute__((ext_vector_type(4)));

#define KST 264   // LDS K-row stride in bf16/f16 elems (528 B)

// Single fused kernel. Block = 256 thr (4 waves) = one 16-q-row tile of one
// batch; wave h owns k-quarter [h*256,+256). Depth-1 wave-private LDS
// pipeline (no barriers in main loop): chunk c+1's K (f32, converted to
// bf16 at ds_write) and mask (raw ints) are loaded while chunk c computes
// from LDS. e parks in f16 regs; one barrier pair for the Z combine; p is
// written once as full 1KB contiguous segments via an LDS transpose; the
// block's partial colsum then drives a block-local GEMV over V with one
// atomicAdd per (b,d). Everything (cvt_k, pack_mask, colsum, attn_out)
// folded: 1 kernel + 1 small memset = 2 dispatches total.
__global__ __launch_bounds__(256, 2) void attn_mega(
    const float* __restrict__ Q, const float* __restrict__ K,
    const float* __restrict__ V, const int* __restrict__ mask,
    float* __restrict__ out0, float* __restrict__ out_p)
{
    const int b    = blockIdx.x >> 6;
    const int qt   = blockIdx.x & 63;
    const int q0   = qt * 16;
    const int tid  = threadIdx.x;
    const int lane = tid & 63;
    const int h    = tid >> 6;       // wave id = k-quarter
    const int m    = lane & 15;      // MFMA A-row / B-col / C-col
    const int kg   = lane >> 4;      // quad: d-slice for A/B, row-group for C

    __shared__ __attribute__((aligned(16))) __bf16 kbuf[4][2][16 * KST]; // 67.6 KB
    __shared__ __attribute__((aligned(16))) int    mbuf[4][2][256];      // 8 KB
    __shared__ float Zs[4][16];
    __shared__ float invZs[16];

    // ---- A fragments: the block's 16 Q rows, f32 -> bf16 once ----
    bf16x8 afrag[8];
    {
        const float* qbase = Q + ((size_t)(b * NSQ + q0 + m)) * ND;
        #pragma unroll
        for (int dc = 0; dc < 8; ++dc) {
            const float* p4 = qbase + dc * 32 + kg * 8;
            float4 x = *(const float4*)(p4);
            float4 y = *(const float4*)(p4 + 4);
            bf16x8 a;
            a[0] = (__bf16)x.x; a[1] = (__bf16)x.y; a[2] = (__bf16)x.z; a[3] = (__bf16)x.w;
            a[4] = (__bf16)y.x; a[5] = (__bf16)y.y; a[6] = (__bf16)y.z; a[7] = (__bf16)y.w;
            afrag[dc] = a;
        }
    }

    // staging geometry
    const float* kq    = K + ((size_t)(b * NSKV + h * 256)) * ND;     // K quarter, f32
    const int*   maskB = mask + ((size_t)(b * NSQ + q0)) * NSKV + h * 256;
    const int    grow  = lane >> 5;          // 0/1
    const int    gcol  = (lane & 31) * 8;    // f32/bf16 col
    const int    mrow  = lane >> 2;          // 0..15
    const int    mcol  = (lane & 3) * 4;     // 0..12

    float  zacc[4] = {0.f, 0.f, 0.f, 0.f};
    f16x4  ebuf[16];
    float4 ga[16];
    int4   mreg;

    #define LDC(c) { \
        const float* _p = kq + (size_t)(c) * 16 * ND + gcol; \
        _Pragma("unroll") \
        for (int r = 0; r < 8; ++r) { \
            ga[2*r]   = *(const float4*)(_p + (size_t)(2*r + grow) * ND); \
            ga[2*r+1] = *(const float4*)(_p + (size_t)(2*r + grow) * ND + 4); \
        } \
        mreg = *(const int4*)(maskB + (size_t)mrow * NSKV + (c) * 16 + mcol); }

    #define STC(pb) { \
        __bf16* _b = &kbuf[h][pb][0]; \
        _Pragma("unroll") \
        for (int r = 0; r < 8; ++r) { \
            bf16x8 t; \
            t[0]=(__bf16)ga[2*r].x;   t[1]=(__bf16)ga[2*r].y; \
            t[2]=(__bf16)ga[2*r].z;   t[3]=(__bf16)ga[2*r].w; \
            t[4]=(__bf16)ga[2*r+1].x; t[5]=(__bf16)ga[2*r+1].y; \
            t[6]=(__bf16)ga[2*r+1].z; t[7]=(__bf16)ga[2*r+1].w; \
            *(bf16x8*)(_b + (2*r + grow) * KST + gcol) = t; \
        } \
        *(int4*)&mbuf[h][pb][mrow * 16 + mcol] = mreg; }

    #define CMP(c, pb) { \
        const __bf16* _b = &kbuf[h][pb][0]; \
        f32x4 acc = {0.f, 0.f, 0.f, 0.f}; \
        _Pragma("unroll") \
        for (int dc = 0; dc < 8; ++dc) { \
            bf16x8 bfr = *(const bf16x8*)(_b + m * KST + dc * 32 + kg * 8); \
            acc = __builtin_amdgcn_mfma_f32_16x16x32_bf16(afrag[dc], bfr, acc, 0, 0, 0); \
        } \
        _Pragma("unroll") \
        for (int i = 0; i < 4; ++i) { \
            int mk = mbuf[h][pb][(kg * 4 + i) * 16 + m]; \
            float e = mk ? __expf(__expf(acc[i]) * 0.0625f) : 0.f; \
            zacc[i] += e; \
            ebuf[c][i] = (_Float16)e; \
        } }

    // prologue: chunk 0 staged; then depth-1 pipeline
    LDC(0);
    STC(0);
    #pragma unroll
    for (int c = 0; c < 16; ++c) {
        if (c < 15) LDC(c + 1);          // in flight across the MFMAs below
        CMP(c, c & 1);
        if (c < 15) STC((c + 1) & 1);    // waits its loads AFTER compute(c)
    }

    // ---- park e into (now free) own-wave staging LDS for coalesced stores ----
    _Float16* myE = (_Float16*)&kbuf[h][0][0];   // 16 x 264 f16 = 8448 B
    #pragma unroll
    for (int c = 0; c < 16; ++c)
        #pragma unroll
        for (int i = 0; i < 4; ++i)
            myE[(kg * 4 + i) * KST + c * 16 + m] = ebuf[c][i];

    // ---- Z: reduce over 16 m-lanes, publish per-wave partials ----
    #pragma unroll
    for (int i = 0; i < 4; ++i) {
        float z = zacc[i];
        z += __shfl_xor(z, 1);
        z += __shfl_xor(z, 2);
        z += __shfl_xor(z, 4);
        z += __shfl_xor(z, 8);
        if (m == 0) Zs[h][kg * 4 + i] = z;
    }
    __syncthreads();
    if (tid < 16)
        invZs[tid] = 1.0f / (Zs[0][tid] + Zs[1][tid] + Zs[2][tid] + Zs[3][tid]);
    __syncthreads();

    // ---- p write: full 1KB contiguous stores; per-block colsum in-pass ----
    float csum[4] = {0.f, 0.f, 0.f, 0.f};
    float* prow = out_p + (size_t)(b * NSQ + q0) * NSKV + h * 256 + lane * 4;
    #pragma unroll
    for (int s = 0; s < 16; ++s) {
        f16x4 ev = *(const f16x4*)&myE[s * KST + lane * 4];
        const float iz = invZs[s];
        float4 pv;
        pv.x = (float)ev[0] * iz; pv.y = (float)ev[1] * iz;
        pv.z = (float)ev[2] * iz; pv.w = (float)ev[3] * iz;
        *(float4*)(prow + (size_t)s * NSKV) = pv;
        csum[0] += pv.x; csum[1] += pv.y; csum[2] += pv.z; csum[3] += pv.w;
    }

    // ---- publish block-local colsum into LDS (reuse dead mbuf) ----
    float* cs = (float*)&mbuf[0][0][0];          // 1024 floats
    float4 fcs; fcs.x = csum[0]; fcs.y = csum[1]; fcs.z = csum[2]; fcs.w = csum[3];
    *(float4*)&cs[h * 256 + lane * 4] = fcs;
    __syncthreads();

    // ---- block-local GEMV: out0[b,:] += cs . V[b,:,:] ----
    const float* Vb = V + (size_t)b * NSKV * ND + tid;
    float oacc = 0.f;
    #pragma unroll 8
    for (int k = 0; k < NSKV; ++k)
        oacc += cs[k] * Vb[(size_t)k * ND];
    atomicAdd(&out0[b * ND + tid], oacc);

    #undef LDC
    #undef STC
    #undef CMP
}

extern "C" void kernel_launch(void* const* d_in, const int* in_sizes, int n_in,
                              void* d_out, int out_size, void* d_ws, size_t ws_size,
                              hipStream_t stream)
{
    (void)in_sizes; (void)n_in; (void)out_size; (void)d_ws; (void)ws_size;
    const float* Q    = (const float*)d_in[0];
    const float* K    = (const float*)d_in[1];
    const float* V    = (const float*)d_in[2];
    const int*   mask = (const int*)d_in[3];

    float* out0 = (float*)d_out;            // (B, D) = 4096 floats
    float* p    = out0 + NB * ND;           // p_attn (B, SQ, SKV)

    hipMemsetAsync(out0, 0, NB * ND * sizeof(float), stream);
    attn_mega<<<NB * 64, 256, 0, stream>>>(Q, K, V, mask, out0, p);
}

// Round 9
// 218.993 us; speedup vs baseline: 1.5417x; 1.5417x over previous
//
#include <hip/hip_runtime.h>

#define NB   16
#define NSQ  1024
#define NSKV 1024
#define ND   256

typedef __bf16    bf16x8 __attribute__((ext_vector_type(8)));
typedef float     f32x4  __attribute__((ext_vector_type(4)));
typedef _Float16  f16x4  __attribute__((ext_vector_type(4)));

#define KST 264   // LDS K-row stride in bf16/f16 elems (528 B)

// ---- prep 1: K (f32) -> bf16 row-major ----
__global__ __launch_bounds__(256) void cvt_k_bf16(
    const float* __restrict__ src, __bf16* __restrict__ dst)
{
    const int i = blockIdx.x * 256 + threadIdx.x;
    const float4* s = (const float4*)src + (size_t)i * 2;
    float4 a = s[0], b = s[1];
    bf16x8 o;
    o[0] = (__bf16)a.x; o[1] = (__bf16)a.y; o[2] = (__bf16)a.z; o[3] = (__bf16)a.w;
    o[4] = (__bf16)b.x; o[5] = (__bf16)b.y; o[6] = (__bf16)b.z; o[7] = (__bf16)b.w;
    ((bf16x8*)dst)[i] = o;
}

// ---- prep 2: pack mask to bits ----
// mw[row*64 + h*16 + m], bit c = (mask[row][h*256 + c*16 + m] != 0).
__global__ __launch_bounds__(256) void pack_mask(
    const int* __restrict__ mask, unsigned* __restrict__ mw)
{
    const int row = blockIdx.x * 4 + (threadIdx.x >> 6);   // b*NSQ + q
    const int l   = threadIdx.x & 63;
    const int4* mrow = (const int4*)(mask + (size_t)row * NSKV) + l * 4;
    unsigned w = 0;
    #pragma unroll
    for (int v = 0; v < 4; ++v) {
        int4 mv = mrow[v];
        w |= (mv.x != 0 ? 1u : 0u) << (v * 4 + 0);
        w |= (mv.y != 0 ? 1u : 0u) << (v * 4 + 1);
        w |= (mv.z != 0 ? 1u : 0u) << (v * 4 + 2);
        w |= (mv.w != 0 ? 1u : 0u) << (v * 4 + 3);
    }
    const int m    = l & 15;
    const int base = l & 48;
    unsigned out = 0;
    #pragma unroll
    for (int c = 0; c < 16; ++c) {
        unsigned v = (unsigned)__shfl((int)w, base | c);
        out |= ((v >> m) & 1u) << c;
    }
    mw[(size_t)row * 64 + l] = out;
}

// ---- main fused kernel ----
// Block = 256 thr (4 waves) = one 32-q-row tile; wave h owns k-quarter
// [h*256,+256). Depth-1 wave-private LDS pipeline (no barriers in main
// loop): chunk c+1's 8 global bf16x8 loads issue, chunk c computes (16
// MFMAs: two 16-row A sets), then c+1 is ds_written. 2x compute per load
// vs R7 -> halved load issue, ~400cyc own-work latency cover. e parks in
// f16 regs (2x32 VGPR); staging LDS (exactly 32x264 f16) is reused as the
// transpose buffer for coalesced 1KB p-stores.
__global__ __launch_bounds__(256, 2) void attn_fused(
    const float* __restrict__ Q, const __bf16* __restrict__ Kb,
    const unsigned* __restrict__ mw, float* __restrict__ out_p,
    float* __restrict__ colsum)
{
    const int b    = blockIdx.x >> 5;
    const int qt   = blockIdx.x & 31;
    const int q0   = qt * 32;
    const int tid  = threadIdx.x;
    const int lane = tid & 63;
    const int h    = tid >> 6;       // wave id = k-quarter
    const int m    = lane & 15;      // MFMA A-row / B-col / C-col
    const int kg   = lane >> 4;      // quad: d-slice for A/B, row-group for C

    __shared__ __attribute__((aligned(16))) __bf16 kbuf[4][2][16 * KST]; // 67.6 KB
    __shared__ float Zs[4][32];
    __shared__ float invZs[32];

    // ---- A fragments: two 16-row sets (rows q0..q0+15, q0+16..q0+31) ----
    bf16x8 afragA[8], afragB[8];
    {
        const float* qbaseA = Q + ((size_t)(b * NSQ + q0 + m)) * ND;
        const float* qbaseB = qbaseA + 16 * ND;
        #pragma unroll
        for (int dc = 0; dc < 8; ++dc) {
            const int off = dc * 32 + kg * 8;
            float4 x = *(const float4*)(qbaseA + off);
            float4 y = *(const float4*)(qbaseA + off + 4);
            bf16x8 a;
            a[0] = (__bf16)x.x; a[1] = (__bf16)x.y; a[2] = (__bf16)x.z; a[3] = (__bf16)x.w;
            a[4] = (__bf16)y.x; a[5] = (__bf16)y.y; a[6] = (__bf16)y.z; a[7] = (__bf16)y.w;
            afragA[dc] = a;
            x = *(const float4*)(qbaseB + off);
            y = *(const float4*)(qbaseB + off + 4);
            a[0] = (__bf16)x.x; a[1] = (__bf16)x.y; a[2] = (__bf16)x.z; a[3] = (__bf16)x.w;
            a[4] = (__bf16)y.x; a[5] = (__bf16)y.y; a[6] = (__bf16)y.z; a[7] = (__bf16)y.w;
            afragB[dc] = a;
        }
    }

    // ---- mask words: 4 per lane per row-set ----
    unsigned mwordA[4], mwordB[4];
    #pragma unroll
    for (int i = 0; i < 4; ++i) {
        mwordA[i] = mw[(size_t)(b * NSQ + q0 + kg * 4 + i) * 64 + h * 16 + m];
        mwordB[i] = mw[(size_t)(b * NSQ + q0 + 16 + kg * 4 + i) * 64 + h * 16 + m];
    }

    // staging geometry: lane stages 8 x 16B; rows 2r+(lane>>5), col (lane&31)*8
    const __bf16* kq   = Kb + ((size_t)(b * NSKV + h * 256)) * ND;
    const int     gcol = (lane & 31) * 8;
    const int     grow = lane >> 5;

    float  zaccA[4] = {0.f, 0.f, 0.f, 0.f};
    float  zaccB[4] = {0.f, 0.f, 0.f, 0.f};
    f16x4  ebufA[16], ebufB[16];
    bf16x8 ga[8];

    #define LDC(c) { \
        const __bf16* _p = kq + (size_t)(c) * 16 * ND + gcol; \
        _Pragma("unroll") \
        for (int r = 0; r < 8; ++r) \
            ga[r] = *(const bf16x8*)(_p + (size_t)(2 * r + grow) * ND); }

    #define STC(pb) { \
        __bf16* _b = &kbuf[h][pb][0]; \
        _Pragma("unroll") \
        for (int r = 0; r < 8; ++r) \
            *(bf16x8*)(_b + (2 * r + grow) * KST + gcol) = ga[r]; }

    #define CMP(afrag, ebuf, mword, zacc, c, pb) { \
        const __bf16* _b = &kbuf[h][pb][0]; \
        f32x4 acc = {0.f, 0.f, 0.f, 0.f}; \
        _Pragma("unroll") \
        for (int dc = 0; dc < 8; ++dc) { \
            bf16x8 bfr = *(const bf16x8*)(_b + m * KST + dc * 32 + kg * 8); \
            acc = __builtin_amdgcn_mfma_f32_16x16x32_bf16(afrag[dc], bfr, acc, 0, 0, 0); \
        } \
        _Pragma("unroll") \
        for (int i = 0; i < 4; ++i) { \
            float e = ((mword[i] >> (c)) & 1u) ? __expf(__expf(acc[i]) * 0.0625f) : 0.f; \
            zacc[i] += e; \
            ebuf[c][i] = (_Float16)e; \
        } }

    // prologue: chunk 0 staged; then depth-1 pipeline
    LDC(0);
    STC(0);
    #pragma unroll
    for (int c = 0; c < 16; ++c) {
        if (c < 15) LDC(c + 1);          // in flight across the 16 MFMAs below
        CMP(afragA, ebufA, mwordA, zaccA, c, c & 1);
        CMP(afragB, ebufB, mwordB, zaccB, c, c & 1);
        if (c < 15) STC((c + 1) & 1);    // waits its loads AFTER the computes
    }

    // ---- park e into (now free) own-wave staging LDS for coalesced stores ----
    _Float16* myE = (_Float16*)&kbuf[h][0][0];   // 32 x 264 f16 = 16896 B = kbuf[h]
    #pragma unroll
    for (int c = 0; c < 16; ++c)
        #pragma unroll
        for (int i = 0; i < 4; ++i) {
            myE[(kg * 4 + i) * KST + c * 16 + m]        = ebufA[c][i];
            myE[(16 + kg * 4 + i) * KST + c * 16 + m]   = ebufB[c][i];
        }

    // ---- Z: reduce over 16 m-lanes, publish per-wave partials ----
    #pragma unroll
    for (int i = 0; i < 4; ++i) {
        float za = zaccA[i], zb = zaccB[i];
        za += __shfl_xor(za, 1); zb += __shfl_xor(zb, 1);
        za += __shfl_xor(za, 2); zb += __shfl_xor(zb, 2);
        za += __shfl_xor(za, 4); zb += __shfl_xor(zb, 4);
        za += __shfl_xor(za, 8); zb += __shfl_xor(zb, 8);
        if (m == 0) {
            Zs[h][kg * 4 + i]      = za;
            Zs[h][16 + kg * 4 + i] = zb;
        }
    }
    __syncthreads();
    if (tid < 32)
        invZs[tid] = 1.0f / (Zs[0][tid] + Zs[1][tid] + Zs[2][tid] + Zs[3][tid]);
    __syncthreads();

    // ---- write phase: full 1KB contiguous stores; colsum in-pass ----
    float csum[4] = {0.f, 0.f, 0.f, 0.f};
    float* prow = out_p + (size_t)(b * NSQ + q0) * NSKV + h * 256 + lane * 4;
    #pragma unroll
    for (int s = 0; s < 32; ++s) {
        f16x4 ev = *(const f16x4*)&myE[s * KST + lane * 4];
        const float iz = invZs[s];
        float4 pv;
        pv.x = (float)ev[0] * iz; pv.y = (float)ev[1] * iz;
        pv.z = (float)ev[2] * iz; pv.w = (float)ev[3] * iz;
        *(float4*)(prow + (size_t)s * NSKV) = pv;
        csum[0] += pv.x; csum[1] += pv.y; csum[2] += pv.z; csum[3] += pv.w;
    }
    #pragma unroll
    for (int j = 0; j < 4; ++j)
        atomicAdd(&colsum[b * NSKV + h * 256 + lane * 4 + j], csum[j]);

    #undef LDC
    #undef STC
    #undef CMP
}

// out[b,d] = sum_k colsum[b,k] * V[b,k,d]; 1024 blocks, 16 k-rows each.
__global__ __launch_bounds__(256) void attn_out_kernel(
    const float* __restrict__ colsum, const float* __restrict__ V,
    float* __restrict__ out)
{
    const int b  = blockIdx.x >> 6;
    const int ks = (blockIdx.x & 63) << 4;
    const int d  = threadIdx.x;
    float acc = 0.f;
    #pragma unroll
    for (int k = 0; k < 16; ++k) {
        acc += colsum[b * NSKV + ks + k] * V[((size_t)(b * NSKV + ks + k)) * ND + d];
    }
    atomicAdd(&out[b * ND + d], acc);
}

extern "C" void kernel_launch(void* const* d_in, const int* in_sizes, int n_in,
                              void* d_out, int out_size, void* d_ws, size_t ws_size,
                              hipStream_t stream)
{
    (void)in_sizes; (void)n_in; (void)out_size; (void)ws_size;
    const float* Q    = (const float*)d_in[0];
    const float* K    = (const float*)d_in[1];
    const float* V    = (const float*)d_in[2];
    const int*   mask = (const int*)d_in[3];

    float* out0 = (float*)d_out;            // (B, D) = 4096 floats
    float* p    = out0 + NB * ND;           // p_attn (B, SQ, SKV)

    float*    colsum = (float*)d_ws;                               // 64 KB
    __bf16*   Kb     = (__bf16*)((char*)d_ws + (64 << 10));        // 8.4 MB
    unsigned* mwbits = (unsigned*)((char*)d_ws + (64 << 10) + (size_t)NB * NSKV * ND * 2); // 4.2 MB

    hipMemsetAsync(colsum, 0, NB * NSKV * sizeof(float), stream);
    hipMemsetAsync(out0, 0, NB * ND * sizeof(float), stream);

    const int nK8 = NB * NSKV * ND / 8;
    cvt_k_bf16<<<nK8 / 256, 256, 0, stream>>>(K, Kb);
    pack_mask<<<NB * NSQ / 4, 256, 0, stream>>>(mask, mwbits);
    attn_fused<<<NB * 32, 256, 0, stream>>>(Q, Kb, mwbits, p, colsum);
    attn_out_kernel<<<NB * 64, 256, 0, stream>>>(colsum, V, out0);
}